// Round 4
// baseline (594.786 us; speedup 1.0000x reference)
//
#include <hip/hip_runtime.h>
#include <math.h>

#define S_LEN  16384
#define NCONV  128
#define NBATCH 256
#define TPB    256
#define ZSLOT  16384  // lds slot holding 0.0f; all OOB taps clamp here

typedef float __attribute__((address_space(1))) as1_float;
typedef float __attribute__((address_space(3))) as3_float;

__device__ __forceinline__ int geti(const int* __restrict__ a, int i, int is64) {
  return is64 ? a[2 * i] : a[i];
}

// OOB-safe LDS read: pos<0 wraps to huge unsigned -> clamps to ZSLOT (=0.0f);
// pos>16383 likewise. One v_min_u32 per load.
__device__ __forceinline__ float lds_clamped(const float* sh, int pos) {
  unsigned idx = (unsigned)pos;
  idx = idx > (unsigned)ZSLOT ? (unsigned)ZSLOT : idx;
  return sh[idx];
}

// ---- tail rotate-walk: 1 ds_read/output, clamped. Short ranges only.
template <int K>
__device__ __forceinline__ void walk_safe(
    const float* sh, const float* __restrict__ w, float bval,
    int d, int p, int r, int q0, int q1, float& mx, int& cnt)
{
  const int n = q1 - q0;
  if (n <= 0) return;
  float win[K];
  int pos = r - p + q0 * d;
#pragma unroll
  for (int t = 0; t < K - 1; ++t) { win[t] = lds_clamped(sh, pos); pos += d; }
  for (int i = 0; i < n; i += K) {
#pragma unroll
    for (int s = 0; s < K; ++s) {
      win[(s + K - 1) % K] = lds_clamped(sh, pos);
      pos += d;
      float a = bval;
#pragma unroll
      for (int t = 0; t < K; ++t) a = fmaf(w[t], win[(s + t) % K], a);
      if (i + s < n) { mx = fmaxf(mx, a); cnt += (a >= 0.f); }
    }
  }
}

// ---- interior chunk pipeline (K outputs/chunk, prefetch one chunk ahead).
// Occupancy is LDS-capped at 2 blocks/CU, so the extra VGPRs are free here.
template <int K, int OFF>
__device__ __forceinline__ void chunk_compute(
    const float (&lo)[K], const float (&hi)[K], const float* __restrict__ w,
    float bval, float& mx, int& cnt)
{
#pragma unroll
  for (int s = 0; s < K; ++s) {
    float a = bval;
#pragma unroll
    for (int t = 0; t < K; ++t) {
      const int u = s + t;
      const float v = (u < K - 1) ? lo[u + OFF] : hi[u - (K - 1)];
      a = fmaf(w[t], v, a);
    }
    mx = fmaxf(mx, a);
    cnt += (a >= 0.f);
  }
}

template <int K>
__device__ __forceinline__ void walk_pipe(
    const float* sh, const float* __restrict__ w, float bval,
    int d, int sbase, int i0, int nc, float& mx, int& cnt)
{
  float P[K], A[K], B[K], C[K];
  int pos = sbase + i0 * d;
#pragma unroll
  for (int t = 0; t < K - 1; ++t) { P[t] = sh[pos]; pos += d; }  // in-bounds
#pragma unroll
  for (int t = 0; t < K; ++t) { A[t] = sh[pos]; pos += d; }      // in-bounds
#pragma unroll
  for (int t = 0; t < K; ++t) { B[t] = lds_clamped(sh, pos); pos += d; }
  chunk_compute<K, 0>(P, A, w, bval, mx, cnt);
  int m = 1;
  while (m + 3 <= nc) {
#pragma unroll
    for (int t = 0; t < K; ++t) { C[t] = lds_clamped(sh, pos); pos += d; }
    chunk_compute<K, 1>(A, B, w, bval, mx, cnt);
#pragma unroll
    for (int t = 0; t < K; ++t) { A[t] = lds_clamped(sh, pos); pos += d; }
    chunk_compute<K, 1>(B, C, w, bval, mx, cnt);
#pragma unroll
    for (int t = 0; t < K; ++t) { B[t] = lds_clamped(sh, pos); pos += d; }
    chunk_compute<K, 1>(C, A, w, bval, mx, cnt);
    m += 3;
  }
  if (m < nc) {
#pragma unroll
    for (int t = 0; t < K; ++t) { C[t] = lds_clamped(sh, pos); pos += d; }
    chunk_compute<K, 1>(A, B, w, bval, mx, cnt);
    ++m;
    if (m < nc) { chunk_compute<K, 1>(B, C, w, bval, mx, cnt); ++m; }
  }
}

template <int K>
__device__ __forceinline__ void walk_class_split(
    const float* sh, const float* __restrict__ w, float bval,
    int d, int p, int r, int q0, int q1, float& mx, int& cnt)
{
  if (q1 <= q0) return;
  const int qlo = (p > r) ? (p - r + d - 1) / d : 0;
  const int qhi = (S_LEN - 1 - r + p) / d - (K - 1);
  int i0 = min(max(qlo, q0), q1);
  int i1 = min(qhi + 1, q1);
  if (i1 < i0) i1 = i0;
  const int nc = (i1 - i0) / K;
  const int i1a = i0 + nc * K;
  walk_safe<K>(sh, w, bval, d, p, r, q0, i0, mx, cnt);
  if (nc > 0) walk_pipe<K>(sh, w, bval, d, r - p, i0, nc, mx, cnt);
  walk_safe<K>(sh, w, bval, d, p, r, i1a, q1, mx, cnt);
}

template <int K>
__device__ __forceinline__ void do_conv(
    const float* sh, const float* __restrict__ w, float bval,
    int d, int p, int L, int tid, float& mx, int& cnt)
{
  if (d >= TPB) {
    // lanes = consecutive classes -> stride-1 LDS addresses, conflict-free
    for (int r = tid; r < d; r += TPB) {
      if (r >= L) continue;
      const int Q = (L - 1 - r) / d + 1;
      walk_class_split<K>(sh, w, bval, d, p, r, 0, Q, mx, cnt);
    }
  } else {
    // Blocked-q partition with per-thread start STAGGER: bank of lane (r,v) at
    // instant i is (r + d*(q0_v + s_v + i)) % 32; s_v = v&31 spreads starts so
    // every wave access covers >=32 consecutive residues -> <=2-way = free.
    const int r  = tid % d;
    const int v  = tid / d;
    const int nv = (TPB - 1 - r) / d + 1;
    const int Q  = (L - 1 - r) / d + 1;
    const int mm = Q / nv;  // ~L/TPB >= 32 always for d<TPB
    const int sA = (mm >= 32) ? (v & 31) : (((v & 31) * mm) >> 5);
    const int vB = v + 1;
    const int sB = (mm >= 32) ? (vB & 31) : (((vB & 31) * mm) >> 5);
    const int q0 = (int)(((long long)Q * v) / nv) + sA;           // s(0)==0
    const int q1 = (v == nv - 1) ? Q
                 : (int)(((long long)Q * vB) / nv) + sB;
    walk_class_split<K>(sh, w, bval, d, p, r, q0, q1, mx, cnt);
  }
}

__global__ __launch_bounds__(TPB) void rocket_feats(
    const float* __restrict__ x, const float* __restrict__ W,
    const float* __restrict__ bias,
    const int* __restrict__ ks, const int* __restrict__ dil,
    const int* __restrict__ pad, float* __restrict__ out)
{
  __shared__ float sh[S_LEN + 4];
  __shared__ float smx[TPB / 64];
  __shared__ int  scnt[TPB / 64];

  const int tid = threadIdx.x;
  const int blk = blockIdx.x;

  // 2 convs per block (one staging amortized over both). XCD swizzle keeps a
  // fixed batch row's staging source hot in one XCD's L2 across its 64 blocks.
  const int xcd  = blk & 7;
  const int slot = blk >> 3;
  const int cp   = slot & (NCONV / 2 - 1);
  const int b    = ((slot >> 6) << 3) | xcd;

  const float* xrow = x + (size_t)b * S_LEN;

  // ---- stage row -> LDS via async global_load_lds, width 16B.
  {
    const int wid = tid >> 6, lane = tid & 63;
    const float* gbase = xrow + lane * 4;
#pragma unroll
    for (int c = 0; c < 16; ++c) {
      const int off = (wid * 16 + c) * 256;  // floats
      __builtin_amdgcn_global_load_lds((const as1_float*)(gbase + off),
                                       (as3_float*)(sh + off), 16, 0, 0);
    }
    if (tid == 0) sh[ZSLOT] = 0.f;
  }
  __syncthreads();

  const int is64 = (ks[1] == 0);
  const int lane = tid & 63, wid = tid >> 6;

  for (int half = 0; half < 2; ++half) {
    const int ci = cp * 2 + half;
    const int k = geti(ks, ci, is64);
    const int d = geti(dil, ci, is64);
    const int p = geti(pad, ci, is64);
    const int L = S_LEN + 2 * p - d * (k - 1);
    const float bval = bias[ci];

    float mx = -INFINITY;
    int cnt = 0;

    if (k == 7) {
      float w[7];
#pragma unroll
      for (int t = 0; t < 7; ++t) w[t] = W[ci * 11 + t];
      do_conv<7>(sh, w, bval, d, p, L, tid, mx, cnt);
    } else if (k == 9) {
      float w[9];
#pragma unroll
      for (int t = 0; t < 9; ++t) w[t] = W[ci * 11 + t];
      do_conv<9>(sh, w, bval, d, p, L, tid, mx, cnt);
    } else {
      float w[11];
#pragma unroll
      for (int t = 0; t < 11; ++t) w[t] = W[ci * 11 + t];
      do_conv<11>(sh, w, bval, d, p, L, tid, mx, cnt);
    }

#pragma unroll
    for (int off = 32; off > 0; off >>= 1) {
      mx = fmaxf(mx, __shfl_down(mx, off, 64));
      cnt += __shfl_down(cnt, off, 64);
    }
    __syncthreads();  // smx/scnt safe to (re)write
    if (lane == 0) { smx[wid] = mx; scnt[wid] = cnt; }
    __syncthreads();
    if (tid == 0) {
      float m = smx[0];
      int c = scnt[0];
#pragma unroll
      for (int ww = 1; ww < TPB / 64; ++ww) { m = fmaxf(m, smx[ww]); c += scnt[ww]; }
      out[(size_t)b * (2 * NCONV) + 2 * ci]     = m;
      out[(size_t)b * (2 * NCONV) + 2 * ci + 1] = (float)c / (float)L;
    }
  }
}

extern "C" void kernel_launch(void* const* d_in, const int* in_sizes, int n_in,
                              void* d_out, int out_size, void* d_ws, size_t ws_size,
                              hipStream_t stream) {
  const float* x    = (const float*)d_in[0];
  const float* W    = (const float*)d_in[1];
  const float* bias = (const float*)d_in[2];
  const int*   ks   = (const int*)d_in[3];
  const int*   dil  = (const int*)d_in[4];
  const int*   pad  = (const int*)d_in[5];
  float* out = (float*)d_out;

  hipLaunchKernelGGL(rocket_feats, dim3(NBATCH * NCONV / 2), dim3(TPB), 0, stream,
                     x, W, bias, ks, dil, pad, out);
}

// Round 5
// 389.467 us; speedup vs baseline: 1.5272x; 1.5272x over previous
//
#include <hip/hip_runtime.h>
#include <math.h>

#define S_LEN  16384
#define NCONV  128
#define NBATCH 256
#define TPB    1024   // 16 waves; one conv per wave
#define ZSLOT  16384  // lds slot holding 0.0f; all OOB taps clamp here

typedef float __attribute__((address_space(1))) as1_float;
typedef float __attribute__((address_space(3))) as3_float;

__device__ __forceinline__ int geti(const int* __restrict__ a, int i, int is64) {
  return is64 ? a[2 * i] : a[i];
}

// wave-uniform value -> SGPR (compiler can't prove uniformity of W[ci*11+t])
__device__ __forceinline__ float sgpr_f(float v) {
  return __int_as_float(__builtin_amdgcn_readfirstlane(__float_as_int(v)));
}

// OOB-safe LDS read: pos<0 wraps to huge unsigned, pos>16383 likewise ->
// clamps to ZSLOT (=0.0f). One v_min_u32 per load.
__device__ __forceinline__ float lds_at(const float* sh, int pos) {
  unsigned idx = (unsigned)pos;
  idx = idx > (unsigned)ZSLOT ? (unsigned)ZSLOT : idx;
  return sh[idx];
}

// rotate-walk: outputs j = r + q*d, q in [q0,q1); K-deep register window,
// 1 ds_read per output. SAFE: clamped reads (boundaries). EXACT: n % K == 0
// so the per-output guard compiles out (interior).
template <int K, bool SAFE, bool EXACT>
__device__ __forceinline__ void walk(
    const float* sh, const float* w, float bval,
    int d, int p, int r, int q0, int q1, float& mx, int& cnt)
{
  const int n = q1 - q0;
  if (n <= 0) return;
  float win[K];
  int pos = r - p + q0 * d;
#pragma unroll
  for (int t = 0; t < K - 1; ++t) {
    win[t] = SAFE ? lds_at(sh, pos) : sh[pos];
    pos += d;
  }
  for (int i = 0; i < n; i += K) {
#pragma unroll
    for (int s = 0; s < K; ++s) {
      win[(s + K - 1) % K] = SAFE ? lds_at(sh, pos) : sh[pos];
      pos += d;
      float a = bval;
#pragma unroll
      for (int t = 0; t < K; ++t) a = fmaf(w[t], win[(s + t) % K], a);
      if (EXACT || (i + s < n)) { mx = fmaxf(mx, a); cnt += (a >= 0.f); }
    }
  }
}

// class [q0,q1) -> safe-lo / exact interior (multiple of K, raw reads) / safe-hi
template <int K>
__device__ __forceinline__ void cls(
    const float* sh, const float* w, float bval,
    int d, int p, int r, int q0, int q1, float& mx, int& cnt)
{
  if (q1 <= q0) return;
  const int qlo = (p > r) ? (p - r + d - 1) / d : 0;
  const int qhi = (S_LEN - 1 - r + p) / d - (K - 1);
  int i0 = min(max(qlo, q0), q1);
  int i1 = min(qhi + 1, q1);
  if (i1 < i0) i1 = i0;
  const int nc = (i1 - i0) / K;
  const int i1a = i0 + nc * K;
  walk<K, true, false>(sh, w, bval, d, p, r, q0, i0, mx, cnt);
  if (nc > 0) walk<K, false, true>(sh, w, bval, d, p, r, i0, i1a, mx, cnt);
  walk<K, true, false>(sh, w, bval, d, p, r, i1a, q1, mx, cnt);
}

// one WAVE handles one conv over the LDS-staged row
template <int K>
__device__ __forceinline__ void conv_wave(
    const float* sh, const float* w, float bval,
    int d, int p, int L, int lane, float& mx, int& cnt)
{
  if (d >= 64) {
    // lane = class; consecutive lanes at consecutive addresses -> conflict-free
    for (int r = lane; r < d; r += 64) {
      if (r >= L) continue;
      const int Q = (L - 1 - r) / d + 1;
      cls<K>(sh, w, bval, d, p, r, 0, Q, mx, cnt);
    }
  } else {
    // split each class's q-range over its lanes; stagger starts mod 32 so a
    // wave access covers a spread of banks (2-way aliasing is free).
    const int r  = lane % d;
    const int v  = lane / d;
    const int nv = (63 - r) / d + 1;
    const int Q  = (L - 1 - r) / d + 1;
    const int mm = Q / nv;
    const int sA = (mm >= 32) ? (v & 31) : (((v & 31) * mm) >> 5);
    const int vB = v + 1;
    const int sB = (mm >= 32) ? (vB & 31) : (((vB & 31) * mm) >> 5);
    const int q0 = (int)(((long long)Q * v) / nv) + sA;   // v==0 -> sA==0
    const int q1 = (v == nv - 1) ? Q
                 : (int)(((long long)Q * vB) / nv) + sB;
    cls<K>(sh, w, bval, d, p, r, q0, q1, mx, cnt);
  }
}

__global__ __launch_bounds__(TPB, 8) void rocket_feats(
    const float* __restrict__ x, const float* __restrict__ W,
    const float* __restrict__ bias,
    const int* __restrict__ ks, const int* __restrict__ dil,
    const int* __restrict__ pad, float* __restrict__ out)
{
  __shared__ float sh[S_LEN + 1];  // 66KB block -> 2 blocks/CU, 32 waves/CU

  const int tid  = threadIdx.x;
  const int blk  = blockIdx.x;     // 2048 = 256 rows x 8 conv-groups
  const int g    = blk & 7;
  const int b    = blk >> 3;
  const int lane = tid & 63, wid = tid >> 6;

  const float* xrow = x + (size_t)b * S_LEN;

  // stage row -> LDS: 64 async 16B-wide wave instrs (4 per wave)
  {
    const float* gb = xrow + lane * 4;
#pragma unroll
    for (int c = 0; c < 4; ++c) {
      const int off = (wid * 4 + c) * 256;  // floats
      __builtin_amdgcn_global_load_lds((const as1_float*)(gb + off),
                                       (as3_float*)(sh + off), 16, 0, 0);
    }
  }
  if (tid == 0) sh[ZSLOT] = 0.f;
  __syncthreads();  // only barrier in the kernel

  const int is64 = (ks[1] == 0);
  const int ci = g * 16 + wid;          // this wave's conv
  const int k = geti(ks, ci, is64);
  const int d = geti(dil, ci, is64);
  const int p = geti(pad, ci, is64);
  const int L = S_LEN + 2 * p - d * (k - 1);
  const float bval = sgpr_f(bias[ci]);

  float mx = -INFINITY;
  int cnt = 0;

  if (k == 7) {
    float w[7];
#pragma unroll
    for (int t = 0; t < 7; ++t) w[t] = sgpr_f(W[ci * 11 + t]);
    conv_wave<7>(sh, w, bval, d, p, L, lane, mx, cnt);
  } else if (k == 9) {
    float w[9];
#pragma unroll
    for (int t = 0; t < 9; ++t) w[t] = sgpr_f(W[ci * 11 + t]);
    conv_wave<9>(sh, w, bval, d, p, L, lane, mx, cnt);
  } else {
    float w[11];
#pragma unroll
    for (int t = 0; t < 11; ++t) w[t] = sgpr_f(W[ci * 11 + t]);
    conv_wave<11>(sh, w, bval, d, p, L, lane, mx, cnt);
  }

  // per-wave shuffle reduction only; no cross-wave reduce needed
#pragma unroll
  for (int off = 32; off > 0; off >>= 1) {
    mx = fmaxf(mx, __shfl_down(mx, off, 64));
    cnt += __shfl_down(cnt, off, 64);
  }
  if (lane == 0) {
    out[(size_t)b * (2 * NCONV) + 2 * ci]     = mx;
    out[(size_t)b * (2 * NCONV) + 2 * ci + 1] = (float)cnt / (float)L;
  }
}

extern "C" void kernel_launch(void* const* d_in, const int* in_sizes, int n_in,
                              void* d_out, int out_size, void* d_ws, size_t ws_size,
                              hipStream_t stream) {
  const float* x    = (const float*)d_in[0];
  const float* W    = (const float*)d_in[1];
  const float* bias = (const float*)d_in[2];
  const int*   ks   = (const int*)d_in[3];
  const int*   dil  = (const int*)d_in[4];
  const int*   pad  = (const int*)d_in[5];
  float* out = (float*)d_out;

  hipLaunchKernelGGL(rocket_feats, dim3(NBATCH * 8), dim3(TPB), 0, stream,
                     x, W, bias, ks, dil, pad, out);
}